// Round 8
// baseline (1230.801 us; speedup 1.0000x reference)
//
#include <hip/hip_runtime.h>
#include <math.h>

// Residual VQ: x (262144,128) fp32, codebooks (3,256,128) fp32.
// Output: [indices as float (262144*3)] ++ [quantized (262144*128)].
//
// ARITHMETIC CONTRACT (round 3, absmax=0 — do not change):
//   M_k  = OpenBLAS sgemm K-loop: sequential FMA chain j=0..127, acc init 0
//   A    = np.sum(r*r): pairwise_sum 8-accumulator scheme, products rounded
//          separately (fmaf(x,x,0) = single-rounded product, blocks fusion)
//   d2_k = (A - 2.0f*M_k) + B_k ; argmin strict < ascending k
//   residual -= q ; quantized = (q0 + q1) + q2  (elementwise fp32, ref order)
//
// ROUND 12: r11 structure (2 items/lane x quarter-dims, LDS codebook at 8:1
// FMA:delivery, 4-piece pipelined left-fold handoff) + two fixes:
//  (1) amdgpu_waves_per_eu(2,4): r11 ran at VGPR=64 with 84MB of scratch
//      write-back — the backend's occupancy-driven RA targets 8 waves/EU
//      and spills the residual to get there (launch_bounds slack is ignored,
//      proven r4). Pinning waves-per-eu to 2..4 legitimizes ~128 VGPR;
//      occupancy is LDS-capped at 2 blocks/CU (4 waves/SIMD) regardless.
//  (2) main-loop g=3..31 split out (prolog 0..2 / epilog 32..34 keep the
//      clamp): codebook reads walk ONE pointer (tc += 128/step) with all
//      32 ds_read_b128 as immediate offsets; B read as one float4 via a
//      walked pointer. Staging permutation moved to the GLOBAL index so
//      LDS writes are lane-linear (kills the 8-way staging-write conflict;
//      global reads stay within the same two 512B segments).
// Bit-exactness: identical arithmetic DAG to r11 (passed absmax=0) — only
// operand addressing and register allocation changed.

constexpr int kItems = 262144;
constexpr int kDim   = 128;
constexpr int kNcb   = 3;
constexpr int kK     = 256;
constexpr int kBlock = 512;          // 8 waves; 256 items/block

__device__ __forceinline__ float sq_rn(float x) {
    return __builtin_fmaf(x, x, 0.0f);   // single-rounded product, blocks contraction
}
#define F3(a, b, c) __builtin_fmaf((a), (b), (c))

// ONLY for codebook B_k staging (global reads)
__device__ __forceinline__ float np_sumsq128(const float* __restrict__ p) {
    float a0 = sq_rn(p[0]), a1 = sq_rn(p[1]), a2 = sq_rn(p[2]), a3 = sq_rn(p[3]),
          a4 = sq_rn(p[4]), a5 = sq_rn(p[5]), a6 = sq_rn(p[6]), a7 = sq_rn(p[7]);
    #pragma unroll
    for (int i = 8; i < 128; i += 8) {
        a0 = a0 + sq_rn(p[i + 0]); a1 = a1 + sq_rn(p[i + 1]);
        a2 = a2 + sq_rn(p[i + 2]); a3 = a3 + sq_rn(p[i + 3]);
        a4 = a4 + sq_rn(p[i + 4]); a5 = a5 + sq_rn(p[i + 5]);
        a6 = a6 + sq_rn(p[i + 6]); a7 = a7 + sq_rn(p[i + 7]);
    }
    return ((a0 + a1) + (a2 + a3)) + ((a4 + a5) + (a6 + a7));
}

// ---- residual: 2 items x 8 float4 (dims 32q..32q+31), all named ----------
#define DECLR(u)  float4 RA_##u, RB_##u;
#define LOADR(u)  RA_##u = xa4[u]; RB_##u = xb4[u];
#define R8(M) M(0) M(1) M(2) M(3) M(4) M(5) M(6) M(7)

// A-fold of this lane's 32 terms ON TOP of accs a0..a7 (ascending local j';
// acc = (32q+4u+e)&7 = (4u+e)&7 since 32q%8==0)
#define AFOLD(R, a0,a1,a2,a3,a4,a5,a6,a7) \
  a0 = a0 + sq_rn(R##_0.x); a1 = a1 + sq_rn(R##_0.y); a2 = a2 + sq_rn(R##_0.z); a3 = a3 + sq_rn(R##_0.w); \
  a4 = a4 + sq_rn(R##_1.x); a5 = a5 + sq_rn(R##_1.y); a6 = a6 + sq_rn(R##_1.z); a7 = a7 + sq_rn(R##_1.w); \
  a0 = a0 + sq_rn(R##_2.x); a1 = a1 + sq_rn(R##_2.y); a2 = a2 + sq_rn(R##_2.z); a3 = a3 + sq_rn(R##_2.w); \
  a4 = a4 + sq_rn(R##_3.x); a5 = a5 + sq_rn(R##_3.y); a6 = a6 + sq_rn(R##_3.z); a7 = a7 + sq_rn(R##_3.w); \
  a0 = a0 + sq_rn(R##_4.x); a1 = a1 + sq_rn(R##_4.y); a2 = a2 + sq_rn(R##_4.z); a3 = a3 + sq_rn(R##_4.w); \
  a4 = a4 + sq_rn(R##_5.x); a5 = a5 + sq_rn(R##_5.y); a6 = a6 + sq_rn(R##_5.z); a7 = a7 + sq_rn(R##_5.w); \
  a0 = a0 + sq_rn(R##_6.x); a1 = a1 + sq_rn(R##_6.y); a2 = a2 + sq_rn(R##_6.z); a3 = a3 + sq_rn(R##_6.w); \
  a4 = a4 + sq_rn(R##_7.x); a5 = a5 + sq_rn(R##_7.y); a6 = a6 + sq_rn(R##_7.z); a7 = a7 + sq_rn(R##_7.w);

// A = np.sum(r*r): 4-round SERIAL handoff across the quarter chain (exact
// left fold); valid at q==3.
#define ACOMPUTE(R, Avar) { \
  float u0=0.f,u1=0.f,u2=0.f,u3=0.f,u4=0.f,u5=0.f,u6=0.f,u7=0.f; \
  if (q == 0) { AFOLD(R,u0,u1,u2,u3,u4,u5,u6,u7) } \
  { float w0=__shfl_up(u0,1),w1=__shfl_up(u1,1),w2=__shfl_up(u2,1),w3=__shfl_up(u3,1), \
          w4=__shfl_up(u4,1),w5=__shfl_up(u5,1),w6=__shfl_up(u6,1),w7=__shfl_up(u7,1); \
    if (q == 1) { u0=w0;u1=w1;u2=w2;u3=w3;u4=w4;u5=w5;u6=w6;u7=w7; \
                  AFOLD(R,u0,u1,u2,u3,u4,u5,u6,u7) } } \
  { float w0=__shfl_up(u0,1),w1=__shfl_up(u1,1),w2=__shfl_up(u2,1),w3=__shfl_up(u3,1), \
          w4=__shfl_up(u4,1),w5=__shfl_up(u5,1),w6=__shfl_up(u6,1),w7=__shfl_up(u7,1); \
    if (q == 2) { u0=w0;u1=w1;u2=w2;u3=w3;u4=w4;u5=w5;u6=w6;u7=w7; \
                  AFOLD(R,u0,u1,u2,u3,u4,u5,u6,u7) } } \
  { float w0=__shfl_up(u0,1),w1=__shfl_up(u1,1),w2=__shfl_up(u2,1),w3=__shfl_up(u3,1), \
          w4=__shfl_up(u4,1),w5=__shfl_up(u5,1),w6=__shfl_up(u6,1),w7=__shfl_up(u7,1); \
    if (q == 3) { u0=w0;u1=w1;u2=w2;u3=w3;u4=w4;u5=w5;u6=w6;u7=w7; \
                  AFOLD(R,u0,u1,u2,u3,u4,u5,u6,u7) } } \
  Avar = ((u0+u1)+(u2+u3))+((u4+u5)+(u6+u7)); }

// one quad column u via pointer tc (immediate offsets): 4 ds_read_b128
// shared by both items + 32 FMAs; e ascending within u, u ascending ->
// per-chain order = ascending local j' (global prefix via pipeline handoff)
#define FOLD_U(u) { \
  const float4 c0 = tc[      (u)*4]; \
  const float4 c1 = tc[32 + (u)*4]; \
  const float4 c2 = tc[64 + (u)*4]; \
  const float4 c3 = tc[96 + (u)*4]; \
  ma0=F3(RA_##u.x,c0.x,ma0); ma0=F3(RA_##u.y,c0.y,ma0); ma0=F3(RA_##u.z,c0.z,ma0); ma0=F3(RA_##u.w,c0.w,ma0); \
  ma1=F3(RA_##u.x,c1.x,ma1); ma1=F3(RA_##u.y,c1.y,ma1); ma1=F3(RA_##u.z,c1.z,ma1); ma1=F3(RA_##u.w,c1.w,ma1); \
  ma2=F3(RA_##u.x,c2.x,ma2); ma2=F3(RA_##u.y,c2.y,ma2); ma2=F3(RA_##u.z,c2.z,ma2); ma2=F3(RA_##u.w,c2.w,ma2); \
  ma3=F3(RA_##u.x,c3.x,ma3); ma3=F3(RA_##u.y,c3.y,ma3); ma3=F3(RA_##u.z,c3.z,ma3); ma3=F3(RA_##u.w,c3.w,ma3); \
  mb0=F3(RB_##u.x,c0.x,mb0); mb0=F3(RB_##u.y,c0.y,mb0); mb0=F3(RB_##u.z,c0.z,mb0); mb0=F3(RB_##u.w,c0.w,mb0); \
  mb1=F3(RB_##u.x,c1.x,mb1); mb1=F3(RB_##u.y,c1.y,mb1); mb1=F3(RB_##u.z,c1.z,mb1); mb1=F3(RB_##u.w,c1.w,mb1); \
  mb2=F3(RB_##u.x,c2.x,mb2); mb2=F3(RB_##u.y,c2.y,mb2); mb2=F3(RB_##u.z,c2.z,mb2); mb2=F3(RB_##u.w,c2.w,mb2); \
  mb3=F3(RB_##u.x,c3.x,mb3); mb3=F3(RB_##u.y,c3.y,mb3); mb3=F3(RB_##u.z,c3.z,mb3); mb3=F3(RB_##u.w,c3.w,mb3); }

// one pipeline step; ARG = finals enabled (compile-time).  Finals (q==3):
// ascending k, strict < ; (A-2m)+B bit-safe fused or not (2m exact).
#define GSTEP(ARG) { \
  float ma0=q?va0:0.f, ma1=q?va1:0.f, ma2=q?va2:0.f, ma3=q?va3:0.f; \
  float mb0=q?vb0:0.f, mb1=q?vb1:0.f, mb2=q?vb2:0.f, mb3=q?vb3:0.f; \
  R8(FOLD_U) \
  if ((ARG) && q == 3) { \
    const float4 bb = sb4[0]; float d; \
    d=(Aa-2.0f*ma0)+bb.x; if(d<bestA){bestA=d;biA=kbi+0;} \
    d=(Aa-2.0f*ma1)+bb.y; if(d<bestA){bestA=d;biA=kbi+1;} \
    d=(Aa-2.0f*ma2)+bb.z; if(d<bestA){bestA=d;biA=kbi+2;} \
    d=(Aa-2.0f*ma3)+bb.w; if(d<bestA){bestA=d;biA=kbi+3;} \
    d=(Ab-2.0f*mb0)+bb.x; if(d<bestB){bestB=d;biB=kbi+0;} \
    d=(Ab-2.0f*mb1)+bb.y; if(d<bestB){bestB=d;biB=kbi+1;} \
    d=(Ab-2.0f*mb2)+bb.z; if(d<bestB){bestB=d;biB=kbi+2;} \
    d=(Ab-2.0f*mb3)+bb.w; if(d<bestB){bestB=d;biB=kbi+3;} \
  } \
  va0=__shfl_up(ma0,1); va1=__shfl_up(ma1,1); va2=__shfl_up(ma2,1); va3=__shfl_up(ma3,1); \
  vb0=__shfl_up(mb0,1); vb1=__shfl_up(mb1,1); vb2=__shfl_up(mb2,1); vb3=__shfl_up(mb3,1); }

// residual -= q (elementwise, ref order): this lane's quarter of both items
#define UPDR(R, selv) { \
  const float4* cw = (const float4*)(cb + ((size_t)c * kK + (selv)) * (size_t)kDim) + q * 8; \
  R##_0.x -= cw[0].x; R##_0.y -= cw[0].y; R##_0.z -= cw[0].z; R##_0.w -= cw[0].w; \
  R##_1.x -= cw[1].x; R##_1.y -= cw[1].y; R##_1.z -= cw[1].z; R##_1.w -= cw[1].w; \
  R##_2.x -= cw[2].x; R##_2.y -= cw[2].y; R##_2.z -= cw[2].z; R##_2.w -= cw[2].w; \
  R##_3.x -= cw[3].x; R##_3.y -= cw[3].y; R##_3.z -= cw[3].z; R##_3.w -= cw[3].w; \
  R##_4.x -= cw[4].x; R##_4.y -= cw[4].y; R##_4.z -= cw[4].z; R##_4.w -= cw[4].w; \
  R##_5.x -= cw[5].x; R##_5.y -= cw[5].y; R##_5.z -= cw[5].z; R##_5.w -= cw[5].w; \
  R##_6.x -= cw[6].x; R##_6.y -= cw[6].y; R##_6.z -= cw[6].z; R##_6.w -= cw[6].w; \
  R##_7.x -= cw[7].x; R##_7.y -= cw[7].y; R##_7.z -= cw[7].z; R##_7.w -= cw[7].w; }

__global__ __launch_bounds__(kBlock)
__attribute__((amdgpu_waves_per_eu(2, 4)))
void rvq_kernel(
    const float* __restrict__ x,
    const float* __restrict__ cb,
    float* __restrict__ out)
{
    extern __shared__ float4 s_cb[];        // 4096 float4 = 64 KiB (one phase,
                                            // layout [row128][jq8][q4])
    __shared__ float4 s_B4[kNcb * kK / 4];  // 3 KiB (B as float4 groups)

    const int tid  = threadIdx.x;
    const int lane = tid & 63;
    const int p    = lane >> 2;             // pair index 0..15
    const int q    = lane & 3;              // quarter 0..3
    const int wave = tid >> 6;              // 0..7

    // B_k = np.sum(cb*cb, axis=-1), bit-exact
    for (int m = tid; m < kNcb * kK; m += kBlock)
        ((float*)s_B4)[m] = np_sumsq128(cb + (size_t)m * kDim);

    // items: 2 per 4-lane group
    const size_t ia = (size_t)blockIdx.x * 256 + wave * 32 + p * 2 + 0;
    const size_t ib = ia + 1;
    const float4* xa4 = (const float4*)(x + ia * kDim + q * 32);
    const float4* xb4 = (const float4*)(x + ib * kDim + q * 32);

    R8(DECLR)
    R8(LOADR)

    float Aa, Ab;
    ACOMPUTE(RA, Aa)
    ACOMPUTE(RB, Ab)

    int sA0=0,sA1=0,sA2=0,sB0=0,sB1=0,sB2=0;

    #pragma unroll
    for (int c = 0; c < kNcb; ++c) {
        float bestA = INFINITY, bestB = INFINITY;
        int   biA = 0, biB = 0;

        #pragma unroll
        for (int ph = 0; ph < 2; ++ph) {
            __syncthreads();   // previous phase fully consumed
            // stage 128 rows; LDS slot linear in lane (conflict-free writes),
            // permutation on the GLOBAL index (same cache lines):
            // slot a=[row][jq*4+qq] holds global float4 [row, qq*8+jq]
            {
                const float4* gsrc = (const float4*)cb + ((size_t)(c * kK + ph * 128)) * 32;
                #pragma unroll
                for (int u = 0; u < 8; ++u) {
                    const int a   = u * kBlock + tid;
                    const int row = a >> 5, rem = a & 31;
                    s_cb[a] = gsrc[row * 32 + (rem & 3) * 8 + (rem >> 2)];
                }
            }
            __syncthreads();

            const int kbase = ph * 128;
            const float4* sb4 = s_B4 + c * 64 + ph * 32;   // finals B, walked
            int kbi = kbase;
            float va0=0.f,va1=0.f,va2=0.f,va3=0.f,vb0=0.f,vb1=0.f,vb2=0.f,vb3=0.f;

            // prolog g=0..2 (no finals; lower clamp only)
            #pragma unroll
            for (int g = 0; g < 3; ++g) {
                int gg = g - q; gg = gg < 0 ? 0 : gg;
                const float4* tc = s_cb + gg * 128 + q;
                GSTEP(0)
            }
            // main g=3..31: unclamped, pointer-walked codebook reads
            {
                const float4* tc = s_cb + (3 - q) * 128 + q;
                #pragma unroll 1
                for (int g = 3; g < 32; ++g) {
                    GSTEP(1)
                    tc += 128; sb4 += 1; kbi += 4;
                }
            }
            // epilog g=32..34 (upper clamp; finals for groups 29..31)
            #pragma unroll
            for (int g = 32; g < 35; ++g) {
                int gg = g - q; gg = gg > 31 ? 31 : gg;
                const float4* tc = s_cb + gg * 128 + q;
                GSTEP(1)
                sb4 += 1; kbi += 4;
            }
        }

        const int selA = __shfl(biA, lane | 3);   // broadcast from q==3
        const int selB = __shfl(biB, lane | 3);
        if (c == 0) { sA0 = selA; sB0 = selB; }
        else if (c == 1) { sA1 = selA; sB1 = selB; }
        else { sA2 = selA; sB2 = selB; }

        if (c < kNcb - 1) {
            UPDR(RA, selA)
            UPDR(RB, selB)
            ACOMPUTE(RA, Aa)
            ACOMPUTE(RB, Ab)
        }
    }

    // ---- outputs
    float* out_idx = out;                             // (items, 3) as float
    float* out_q   = out + (size_t)kItems * kNcb;     // (items, 128)
    if (q == 0) {
        out_idx[ia*3+0] = (float)sA0; out_idx[ia*3+1] = (float)sA1; out_idx[ia*3+2] = (float)sA2;
        out_idx[ib*3+0] = (float)sB0; out_idx[ib*3+1] = (float)sB1; out_idx[ib*3+2] = (float)sB2;
    }
    {
        const float4* g0 = (const float4*)(cb + ((size_t)0*kK + sA0)*kDim) + q*8;
        const float4* g1 = (const float4*)(cb + ((size_t)1*kK + sA1)*kDim) + q*8;
        const float4* g2 = (const float4*)(cb + ((size_t)2*kK + sA2)*kDim) + q*8;
        float4* qo = (float4*)(out_q + ia * kDim) + q*8;
        #pragma unroll
        for (int u = 0; u < 8; ++u) {
            const float4 v0 = g0[u], v1 = g1[u], v2 = g2[u];
            float4 w;
            w.x = (v0.x + v1.x) + v2.x; w.y = (v0.y + v1.y) + v2.y;
            w.z = (v0.z + v1.z) + v2.z; w.w = (v0.w + v1.w) + v2.w;
            qo[u] = w;                 // ((0+q0)+q1)+q2 in fp32, ref order
        }
    }
    {
        const float4* g0 = (const float4*)(cb + ((size_t)0*kK + sB0)*kDim) + q*8;
        const float4* g1 = (const float4*)(cb + ((size_t)1*kK + sB1)*kDim) + q*8;
        const float4* g2 = (const float4*)(cb + ((size_t)2*kK + sB2)*kDim) + q*8;
        float4* qo = (float4*)(out_q + ib * kDim) + q*8;
        #pragma unroll
        for (int u = 0; u < 8; ++u) {
            const float4 v0 = g0[u], v1 = g1[u], v2 = g2[u];
            float4 w;
            w.x = (v0.x + v1.x) + v2.x; w.y = (v0.y + v1.y) + v2.y;
            w.z = (v0.z + v1.z) + v2.z; w.w = (v0.w + v1.w) + v2.w;
            qo[u] = w;
        }
    }
}

extern "C" void kernel_launch(void* const* d_in, const int* in_sizes, int n_in,
                              void* d_out, int out_size, void* d_ws, size_t ws_size,
                              hipStream_t stream) {
    const float* x  = (const float*)d_in[0];
    const float* cb = (const float*)d_in[1];
    float* out = (float*)d_out;
    static bool attr_set = false;
    if (!attr_set) {
        hipFuncSetAttribute((const void*)rvq_kernel,
                            hipFuncAttributeMaxDynamicSharedMemorySize, 65536);
        attr_set = true;
    }
    rvq_kernel<<<kItems / 256, kBlock, 65536, stream>>>(x, cb, out);
}